// Round 7
// baseline (92.364 us; speedup 1.0000x reference)
//
#include <hip/hip_runtime.h>

// Chamfer distance: srcs, tgts [B=8, D=3, N=4096] f32 -> scalar f32
//   out = mean_{b,j} min_i |s_i - t_j|^2  +  mean_{b,i} min_j |s_i - t_j|^2
//
// Round 7: SMEM-fed inner loop (targets pre-packed, wave-uniform float4
// reads -> s_load; zero LDS/VMEM in the loop) + max occupancy: QQ=4 cuts
// VGPRs to ~40, __launch_bounds__(256,8) -> 8 waves/SIMD, grid 2048 =
// 8 blocks/CU (whole grid resident). Scalar v_fma (pk_fma is same FLOP
// rate on gfx950) + inline-asm v_min3_f32.
// Fixed harness floor: ~42 us d_ws re-poison + ~6 us restores/gaps.

#define CD_B 8
#define CD_N 4096
#define BLK 256
#define TCH 32                 // target chunks
#define TPB (CD_N / TCH)       // 128 targets per block
#define QQ 4                   // queries per thread
#define QPB (BLK * QQ)         // 1024 queries per block
#define QCH (CD_N / QPB)       // 4 query chunks
#define NQ (2 * CD_B * CD_N)   // 65536 total queries
#define MINS_FLOATS (TCH * NQ) // 8 MB ws region for partial mins

__device__ __forceinline__ float min3f(float m, float a, float b) {
  asm("v_min3_f32 %0, %1, %2, %0" : "+v"(m) : "v"(a), "v"(b));
  return m;
}

// P[(dir*B+b)*N + j] = (-2x, -2y, -2z, |t|^2)
__global__ __launch_bounds__(BLK) void cd_prep(
    const float* __restrict__ srcs, const float* __restrict__ tgts,
    float4* __restrict__ P, float* __restrict__ out) {
  const int g   = blockIdx.x * BLK + threadIdx.x;  // 65536 targets total
  const int j   = g & (CD_N - 1);                  // 12 bits
  const int b   = (g >> 12) & (CD_B - 1);          // 3 bits
  const int dir = g >> 15;                         // 1 bit
  const float* tb = (dir ? srcs : tgts) + b * 3 * CD_N;
  float x = tb[j], y = tb[CD_N + j], z = tb[2 * CD_N + j];
  float w = fmaf(x, x, fmaf(y, y, z * z));
  P[(size_t)(dir * CD_B + b) * CD_N + j] =
      make_float4(-2.f * x, -2.f * y, -2.f * z, w);
  if (g == 0) out[0] = 0.0f;  // stream-ordered before cd_reduce
}

// ws layout: float ws[TCH][NQ]
__global__ __launch_bounds__(BLK, 8) void cd_partial(
    const float* __restrict__ srcs, const float* __restrict__ tgts,
    const float4* __restrict__ P, float* __restrict__ ws) {
  const int bid = blockIdx.x;               // 2048 blocks
  const int tc  = bid & (TCH - 1);          // 5 bits
  const int qc  = (bid >> 5) & (QCH - 1);   // 2 bits
  const int b   = (bid >> 7) & (CD_B - 1);  // 3 bits
  const int dir = bid >> 10;                // 1 bit
  const int tid = threadIdx.x;

  const float* qb = (dir ? tgts : srcs) + b * 3 * CD_N;

  // Loop-invariant query registers.
  float sx[QQ], sy[QQ], sz[QQ];
  const int q0 = qc * QPB + tid;
#pragma unroll
  for (int qq = 0; qq < QQ; ++qq) {
    int q = q0 + qq * BLK;
    sx[qq] = qb[q];
    sy[qq] = qb[CD_N + q];
    sz[qq] = qb[2 * CD_N + q];
  }

  float mm[QQ];
#pragma unroll
  for (int qq = 0; qq < QQ; ++qq) mm[qq] = 3.4e38f;

  // Wave-uniform target reads -> SGPRs (scalar cache; no LDS, no VMEM).
  const float4* __restrict__ Pp =
      P + (size_t)(dir * CD_B + b) * CD_N + tc * TPB;
#pragma unroll 4
  for (int g = 0; g < TPB / 2; ++g) {
    float4 t0 = Pp[2 * g];      // (-2x,-2y,-2z,w)  [SGPRs]
    float4 t1 = Pp[2 * g + 1];
#pragma unroll
    for (int qq = 0; qq < QQ; ++qq) {
      float v0 = fmaf(sx[qq], t0.x, fmaf(sy[qq], t0.y, fmaf(sz[qq], t0.z, t0.w)));
      float v1 = fmaf(sx[qq], t1.x, fmaf(sy[qq], t1.y, fmaf(sz[qq], t1.z, t1.w)));
      mm[qq] = min3f(mm[qq], v0, v1);
    }
  }

  const int gqbase = (dir * CD_B + b) * CD_N + qc * QPB + tid;
  float* wrow = ws + (size_t)tc * NQ;
#pragma unroll
  for (int qq = 0; qq < QQ; ++qq) {
    float ssq = fmaf(sx[qq], sx[qq], fmaf(sy[qq], sy[qq], sz[qq] * sz[qq]));
    wrow[gqbase + qq * BLK] = mm[qq] + ssq;  // full min-dist partial
  }
}

__global__ __launch_bounds__(BLK) void cd_reduce(
    const float* __restrict__ ws, float* __restrict__ out) {
  const int q = blockIdx.x * BLK + threadIdx.x;  // 65536 threads
  float m0 = ws[q];
  float m1 = ws[(size_t)1 * NQ + q];
#pragma unroll
  for (int tc = 2; tc < TCH; tc += 2) {
    m0 = fminf(m0, ws[(size_t)tc * NQ + q]);
    m1 = fminf(m1, ws[(size_t)(tc + 1) * NQ + q]);
  }
  float m = fminf(m0, m1);

  for (int off = 32; off; off >>= 1) m += __shfl_down(m, off, 64);
  __shared__ float wsum[BLK / 64];
  if ((threadIdx.x & 63) == 0) wsum[threadIdx.x >> 6] = m;
  __syncthreads();
  if (threadIdx.x == 0) {
    float s = (wsum[0] + wsum[1]) + (wsum[2] + wsum[3]);
    atomicAdd(out, s * (1.0f / (float)(CD_B * CD_N)));
  }
}

extern "C" void kernel_launch(void* const* d_in, const int* in_sizes, int n_in,
                              void* d_out, int out_size, void* d_ws, size_t ws_size,
                              hipStream_t stream) {
  const float* srcs = (const float*)d_in[0];
  const float* tgts = (const float*)d_in[1];
  float* out = (float*)d_out;
  float* ws_mins = (float*)d_ws;                                 // 8 MB
  float4* P = (float4*)((char*)d_ws + (size_t)MINS_FLOATS * 4);  // +1 MB

  cd_prep<<<NQ / BLK, BLK, 0, stream>>>(srcs, tgts, P, out);
  cd_partial<<<2 * CD_B * QCH * TCH, BLK, 0, stream>>>(srcs, tgts, P, ws_mins);
  cd_reduce<<<NQ / BLK, BLK, 0, stream>>>(ws_mins, out);
}

// Round 8
// 87.732 us; speedup vs baseline: 1.0528x; 1.0528x over previous
//
#include <hip/hip_runtime.h>

// Chamfer distance: srcs, tgts [B=8, D=3, N=4096] f32 -> scalar f32
//   out = mean_{b,j} min_i |s_i - t_j|^2  +  mean_{b,i} min_j |s_i - t_j|^2
//
// Round 8: QQ=16 queries/thread (one broadcast ds_read_b128 feeds
// 64 lanes x 16 queries = 1024 pairs), TCH=64 keeps grid at 1024 blocks
// (4 blocks/CU, 16 waves/CU). LDS-pipe load halves; VALU 3.5 inst/pair.
// Structure otherwise identical to round 5 (best so far).
// Fixed harness floor: ~47.5 us (41.7 ws-poison + ~5.8 restores/gaps).

#define CD_B 8
#define CD_N 4096
#define BLK 256
#define TCH 64                 // target chunks
#define TPB (CD_N / TCH)       // 64 targets per block
#define QQ 16                  // queries per thread
#define QPB (BLK * QQ)         // 4096 queries per block
#define QCH (CD_N / QPB)       // 1 query chunk
#define NQ (2 * CD_B * CD_N)   // 65536 total queries
#define MINS_FLOATS (TCH * NQ) // 16 MB ws region for partial mins

__device__ __forceinline__ float min3f(float m, float a, float b) {
  asm("v_min3_f32 %0, %1, %2, %0" : "+v"(m) : "v"(a), "v"(b));
  return m;
}

// ws layout: float ws[TCH][NQ]
__global__ __launch_bounds__(BLK) void cd_partial(
    const float* __restrict__ srcs, const float* __restrict__ tgts,
    float* __restrict__ ws, float* __restrict__ out) {
  const int bid = blockIdx.x;               // 1024 blocks
  const int tc  = bid & (TCH - 1);          // 6 bits
  const int b   = (bid >> 6) & (CD_B - 1);  // 3 bits
  const int dir = bid >> 9;                 // 1 bit
  const int tid = threadIdx.x;

  const float* qb = (dir ? tgts : srcs) + b * 3 * CD_N;
  const float* tb = (dir ? srcs : tgts) + b * 3 * CD_N;

  // T[j] = (-2x, -2y, -2z, |t|^2)
  __shared__ float4 T[TPB];  // 1 KiB
  if (tid < TPB) {
    int gj = tc * TPB + tid;
    float x = tb[gj], y = tb[CD_N + gj], z = tb[2 * CD_N + gj];
    float w = fmaf(x, x, fmaf(y, y, z * z));
    T[tid] = make_float4(-2.0f * x, -2.0f * y, -2.0f * z, w);
  }
  if (bid == 0 && tid == 0) out[0] = 0.0f;  // stream-ordered before cd_reduce
  __syncthreads();

  float sx[QQ], sy[QQ], sz[QQ];
#pragma unroll
  for (int qq = 0; qq < QQ; ++qq) {
    int q = tid + qq * BLK;
    sx[qq] = qb[q];
    sy[qq] = qb[CD_N + q];
    sz[qq] = qb[2 * CD_N + q];
  }

  float mm[QQ];
#pragma unroll
  for (int qq = 0; qq < QQ; ++qq) mm[qq] = 3.4e38f;

  // 4-target software pipeline: load next 4 while computing current 4.
  float4 c0 = T[0], c1 = T[1], c2 = T[2], c3 = T[3];
  for (int j = 4; j < TPB; j += 4) {
    float4 n0 = T[j], n1 = T[j + 1], n2 = T[j + 2], n3 = T[j + 3];
#pragma unroll
    for (int qq = 0; qq < QQ; ++qq) {
      float v0 = fmaf(sx[qq], c0.x, fmaf(sy[qq], c0.y, fmaf(sz[qq], c0.z, c0.w)));
      float v1 = fmaf(sx[qq], c1.x, fmaf(sy[qq], c1.y, fmaf(sz[qq], c1.z, c1.w)));
      float v2 = fmaf(sx[qq], c2.x, fmaf(sy[qq], c2.y, fmaf(sz[qq], c2.z, c2.w)));
      float v3 = fmaf(sx[qq], c3.x, fmaf(sy[qq], c3.y, fmaf(sz[qq], c3.z, c3.w)));
      mm[qq] = min3f(mm[qq], v0, v1);
      mm[qq] = min3f(mm[qq], v2, v3);
    }
    c0 = n0; c1 = n1; c2 = n2; c3 = n3;
  }
#pragma unroll
  for (int qq = 0; qq < QQ; ++qq) {
    float v0 = fmaf(sx[qq], c0.x, fmaf(sy[qq], c0.y, fmaf(sz[qq], c0.z, c0.w)));
    float v1 = fmaf(sx[qq], c1.x, fmaf(sy[qq], c1.y, fmaf(sz[qq], c1.z, c1.w)));
    float v2 = fmaf(sx[qq], c2.x, fmaf(sy[qq], c2.y, fmaf(sz[qq], c2.z, c2.w)));
    float v3 = fmaf(sx[qq], c3.x, fmaf(sy[qq], c3.y, fmaf(sz[qq], c3.z, c3.w)));
    mm[qq] = min3f(mm[qq], v0, v1);
    mm[qq] = min3f(mm[qq], v2, v3);
  }

  const int gqbase = (dir * CD_B + b) * CD_N + tid;
  float* wrow = ws + (size_t)tc * NQ;
#pragma unroll
  for (int qq = 0; qq < QQ; ++qq) {
    float ssq = fmaf(sx[qq], sx[qq], fmaf(sy[qq], sy[qq], sz[qq] * sz[qq]));
    wrow[gqbase + qq * BLK] = mm[qq] + ssq;  // full min-dist partial
  }
}

__global__ __launch_bounds__(BLK) void cd_reduce(
    const float* __restrict__ ws, float* __restrict__ out) {
  const int q = blockIdx.x * BLK + threadIdx.x;  // 65536 threads
  float m0 = ws[q];
  float m1 = ws[(size_t)1 * NQ + q];
#pragma unroll
  for (int tc = 2; tc < TCH; tc += 2) {
    m0 = fminf(m0, ws[(size_t)tc * NQ + q]);
    m1 = fminf(m1, ws[(size_t)(tc + 1) * NQ + q]);
  }
  float m = fminf(m0, m1);

  for (int off = 32; off; off >>= 1) m += __shfl_down(m, off, 64);
  __shared__ float wsum[BLK / 64];
  if ((threadIdx.x & 63) == 0) wsum[threadIdx.x >> 6] = m;
  __syncthreads();
  if (threadIdx.x == 0) {
    float s = (wsum[0] + wsum[1]) + (wsum[2] + wsum[3]);
    atomicAdd(out, s * (1.0f / (float)(CD_B * CD_N)));
  }
}

extern "C" void kernel_launch(void* const* d_in, const int* in_sizes, int n_in,
                              void* d_out, int out_size, void* d_ws, size_t ws_size,
                              hipStream_t stream) {
  const float* srcs = (const float*)d_in[0];
  const float* tgts = (const float*)d_in[1];
  float* out = (float*)d_out;
  float* ws_mins = (float*)d_ws;  // 16 MB

  cd_partial<<<2 * CD_B * QCH * TCH, BLK, 0, stream>>>(srcs, tgts, ws_mins, out);
  cd_reduce<<<NQ / BLK, BLK, 0, stream>>>(ws_mins, out);
}

// Round 9
// 86.309 us; speedup vs baseline: 1.0702x; 1.0165x over previous
//
#include <hip/hip_runtime.h>

// Chamfer distance: srcs, tgts [B=8, D=3, N=4096] f32 -> scalar f32
//   out = mean_{b,j} min_i |s_i - t_j|^2  +  mean_{b,i} min_j |s_i - t_j|^2
//
// Round 9: SYMMETRIC tiling — the pair matrix is shared by both directions,
// so compute each of the 134M unique pairs ONCE (rounds 2-8 did 2x).
// Block = 128x128 tile, thread = 8x8 register sub-tile, 5 inst/pair
// (4 fma-chain incl. rank-1 base add + shared v_min3 folds).
// Row mins: shfl_xor over lane bits 0-3 (tx). Col mins: shfl_xor 16/32 +
// 2KB LDS across the 4 waves. Partials -> ws[32][rows||cols], reduce kernel.
// Fixed harness floor: ~42-46 us d_ws re-poison + ~6 us restores/gaps.

#define CD_B 8
#define CD_N 4096
#define BLK 256
#define TIL 128               // tile edge
#define NT  (CD_N / TIL)      // 32 tiles per axis
#define QI 8                  // rows per thread
#define QJ 8                  // cols per thread
#define NQ (2 * CD_B * CD_N)  // 65536 = 32768 row-entries + 32768 col-entries

__device__ __forceinline__ float min3f(float m, float a, float b) {
  asm("v_min3_f32 %0, %1, %2, %0" : "+v"(m) : "v"(a), "v"(b));
  return m;
}

// ws layout: float ws[NT][NQ]  (8 MB)
__global__ __launch_bounds__(BLK) void cd_tile(
    const float* __restrict__ srcs, const float* __restrict__ tgts,
    float* __restrict__ ws, float* __restrict__ out) {
  const int bid = blockIdx.x;            // 8192 blocks
  const int jt  = bid & (NT - 1);        // 5 bits
  const int it  = (bid >> 5) & (NT - 1); // 5 bits
  const int b   = bid >> 10;             // 3 bits
  const int tid = threadIdx.x;
  const int tx  = tid & 15;              // j-direction (lane bits 0-3)
  const int ty  = tid >> 4;              // i-direction

  if (bid == 0 && tid == 0) out[0] = 0.0f;  // stream-ordered before cd_reduce

  const float* sb = srcs + b * 3 * CD_N;
  const float* tb = tgts + b * 3 * CD_N;
  const int i0 = it * TIL + ty * QI;
  const int j0 = jt * TIL + tx * QJ;

  // Register-resident coordinates: 8 srcs rows, 8 tgts cols.
  float sx[QI], sy[QI], sz[QI], sw[QI];
  float ux[QJ], uy[QJ], uz[QJ], uw[QJ];
  *(float4*)&sx[0] = *(const float4*)(sb + i0);
  *(float4*)&sx[4] = *(const float4*)(sb + i0 + 4);
  *(float4*)&sy[0] = *(const float4*)(sb + CD_N + i0);
  *(float4*)&sy[4] = *(const float4*)(sb + CD_N + i0 + 4);
  *(float4*)&sz[0] = *(const float4*)(sb + 2 * CD_N + i0);
  *(float4*)&sz[4] = *(const float4*)(sb + 2 * CD_N + i0 + 4);
  *(float4*)&ux[0] = *(const float4*)(tb + j0);
  *(float4*)&ux[4] = *(const float4*)(tb + j0 + 4);
  *(float4*)&uy[0] = *(const float4*)(tb + CD_N + j0);
  *(float4*)&uy[4] = *(const float4*)(tb + CD_N + j0 + 4);
  *(float4*)&uz[0] = *(const float4*)(tb + 2 * CD_N + j0);
  *(float4*)&uz[4] = *(const float4*)(tb + 2 * CD_N + j0 + 4);
#pragma unroll
  for (int u = 0; u < QI; ++u)
    sw[u] = fmaf(sx[u], sx[u], fmaf(sy[u], sy[u], sz[u] * sz[u]));
#pragma unroll
  for (int u = 0; u < QJ; ++u) {
    uw[u] = fmaf(ux[u], ux[u], fmaf(uy[u], uy[u], uz[u] * uz[u]));
    ux[u] *= -2.0f; uy[u] *= -2.0f; uz[u] *= -2.0f;
  }

  float rm[QI], cm[QJ];
#pragma unroll
  for (int u = 0; u < QI; ++u) rm[u] = 3.4e38f;
#pragma unroll
  for (int u = 0; u < QJ; ++u) cm[u] = 3.4e38f;

  // 8x8 register tile in 2x2 micro-blocks: 20 inst / 4 pairs.
#pragma unroll
  for (int i = 0; i < QI; i += 2) {
#pragma unroll
    for (int j = 0; j < QJ; j += 2) {
      float b00 = sw[i] + uw[j];
      float b01 = sw[i] + uw[j + 1];
      float b10 = sw[i + 1] + uw[j];
      float b11 = sw[i + 1] + uw[j + 1];
      float v00 = fmaf(sx[i], ux[j], fmaf(sy[i], uy[j], fmaf(sz[i], uz[j], b00)));
      float v01 = fmaf(sx[i], ux[j+1], fmaf(sy[i], uy[j+1], fmaf(sz[i], uz[j+1], b01)));
      float v10 = fmaf(sx[i+1], ux[j], fmaf(sy[i+1], uy[j], fmaf(sz[i+1], uz[j], b10)));
      float v11 = fmaf(sx[i+1], ux[j+1], fmaf(sy[i+1], uy[j+1], fmaf(sz[i+1], uz[j+1], b11)));
      rm[i]     = min3f(rm[i],     v00, v01);
      rm[i + 1] = min3f(rm[i + 1], v10, v11);
      cm[j]     = min3f(cm[j],     v00, v10);
      cm[j + 1] = min3f(cm[j + 1], v01, v11);
    }
  }

  // Row mins: reduce across tx = lane bits 0-3 (in-wave shuffles).
#pragma unroll
  for (int u = 0; u < QI; ++u) {
    float r = rm[u];
    r = fminf(r, __shfl_xor(r, 1, 64));
    r = fminf(r, __shfl_xor(r, 2, 64));
    r = fminf(r, __shfl_xor(r, 4, 64));
    r = fminf(r, __shfl_xor(r, 8, 64));
    rm[u] = r;
  }
  if (tx == 0) {
    float* wrow = ws + (size_t)jt * NQ + b * CD_N + i0;
    *(float4*)&wrow[0] = make_float4(rm[0], rm[1], rm[2], rm[3]);
    *(float4*)&wrow[4] = make_float4(rm[4], rm[5], rm[6], rm[7]);
  }

  // Col mins: reduce ty&3 in-wave (lane bits 4-5), then across 4 waves via LDS.
#pragma unroll
  for (int u = 0; u < QJ; ++u) {
    float c = cm[u];
    c = fminf(c, __shfl_xor(c, 16, 64));
    c = fminf(c, __shfl_xor(c, 32, 64));
    cm[u] = c;
  }
  __shared__ float C[4][TIL];  // 2 KB
  if ((ty & 3) == 0) {
#pragma unroll
    for (int u = 0; u < QJ; ++u) C[ty >> 2][tx * QJ + u] = cm[u];
  }
  __syncthreads();
  if (tid < TIL) {
    float c = fminf(fminf(C[0][tid], C[1][tid]), fminf(C[2][tid], C[3][tid]));
    ws[(size_t)it * NQ + CD_B * CD_N + b * CD_N + jt * TIL + tid] = c;
  }
}

__global__ __launch_bounds__(BLK) void cd_reduce(
    const float* __restrict__ ws, float* __restrict__ out) {
  const int q = blockIdx.x * BLK + threadIdx.x;  // 65536 threads
  float m0 = ws[q];
  float m1 = ws[(size_t)1 * NQ + q];
#pragma unroll
  for (int k = 2; k < NT; k += 2) {
    m0 = fminf(m0, ws[(size_t)k * NQ + q]);
    m1 = fminf(m1, ws[(size_t)(k + 1) * NQ + q]);
  }
  float m = fminf(m0, m1);

  for (int off = 32; off; off >>= 1) m += __shfl_down(m, off, 64);
  __shared__ float wsum[BLK / 64];
  if ((threadIdx.x & 63) == 0) wsum[threadIdx.x >> 6] = m;
  __syncthreads();
  if (threadIdx.x == 0) {
    float s = (wsum[0] + wsum[1]) + (wsum[2] + wsum[3]);
    atomicAdd(out, s * (1.0f / (float)(CD_B * CD_N)));
  }
}

extern "C" void kernel_launch(void* const* d_in, const int* in_sizes, int n_in,
                              void* d_out, int out_size, void* d_ws, size_t ws_size,
                              hipStream_t stream) {
  const float* srcs = (const float*)d_in[0];
  const float* tgts = (const float*)d_in[1];
  float* out = (float*)d_out;
  float* ws = (float*)d_ws;  // NT*NQ*4 = 8 MB

  cd_tile<<<CD_B * NT * NT, BLK, 0, stream>>>(srcs, tgts, ws, out);
  cd_reduce<<<NQ / BLK, BLK, 0, stream>>>(ws, out);
}